// Round 3
// baseline (1453.067 us; speedup 1.0000x reference)
//
#include <hip/hip_runtime.h>

// RNN B=256 T=2048 I=64 H=256 — one workgroup per sample (256 CUs), MFMA matvec.
// Round 3: 256 threads = 4 waves (was 8). B-fragments (h, x) are identical
// across waves, so LDS-read traffic scales with wave count while MFMA work is
// fixed -> fewer waves = fewer redundant ds_read_b128 through the per-CU LDS
// pipe (88 -> 44 LDS instr/step). Each wave owns 64 rows = 4 M-tiles; weights
// stay resident in VGPRs as f16 A-fragments; h double-buffered in LDS (f16).
// One __syncthreads per step.

static constexpr int nB = 256;
static constexpr int nT = 2048;
static constexpr int nI = 64;
static constexpr int nH = 256;
static constexpr int XBLK = 32;     // timesteps of x staged per block
static constexpr int THREADS = 256; // 4 waves; wave w owns rows [64w, 64w+64)

typedef _Float16 f16x8 __attribute__((ext_vector_type(8)));
typedef float f32x4 __attribute__((ext_vector_type(4)));

__device__ __forceinline__ float fast_tanh(float x) {
  float a = fabsf(x);
  float e = __expf(-2.0f * a);           // in (0,1], never overflows
  float r = (1.0f - e) / (1.0f + e);
  return copysignf(r, x);
}

__global__ __launch_bounds__(THREADS, 1)
void rnn_mfma4(const float* __restrict__ x, const int* __restrict__ lengths,
               const float* __restrict__ Wih, const float* __restrict__ Whh,
               const float* __restrict__ bih, const float* __restrict__ bhh,
               const float* __restrict__ Wfc, const float* __restrict__ bfc,
               float* __restrict__ out)
{
  __shared__ __align__(16) _Float16 hbuf[2][nH];          // 1 KB
  __shared__ __align__(16) _Float16 xbuf[2][XBLK * nI];   // 8 KB
  __shared__ float red[4];

  const int b   = blockIdx.x;
  const int tid = threadIdx.x;
  const int w   = tid >> 6;       // wave 0..3
  const int l   = tid & 63;
  const int q   = l >> 4;         // quad 0..3
  const int n   = l & 15;         // MFMA column lane
  const int len = lengths[b];     // in [1, nT]
  const float* xb = x + (size_t)b * nT * nI;

  // ---- preamble: pack this wave's W rows into A-fragments (f16)
  // A layout (16x16x32): lane holds A[m = lane&15][k = 8*(lane>>4) + j], j=0..7
  f16x8 Ah[4][8];   // [m-tile][k-tile] over W_hh: rows 64w+16mt+n, k 32kt+8q+j
  f16x8 Ax[4][2];   // over W_ih (I=64 -> 2 k-tiles)
#pragma unroll
  for (int mt = 0; mt < 4; ++mt) {
    const int row = 64 * w + 16 * mt + n;
#pragma unroll
    for (int kt = 0; kt < 8; ++kt) {
      const float* src = Whh + row * nH + 32 * kt + 8 * q;
      f16x8 a;
#pragma unroll
      for (int j = 0; j < 8; ++j) a[j] = (_Float16)src[j];
      Ah[mt][kt] = a;
    }
#pragma unroll
    for (int kt = 0; kt < 2; ++kt) {
      const float* src = Wih + row * nI + 32 * kt + 8 * q;
      f16x8 a;
#pragma unroll
      for (int j = 0; j < 8; ++j) a[j] = (_Float16)src[j];
      Ax[mt][kt] = a;
    }
  }
  // bias in C layout: reg r <-> row 64w + 16mt + 4q + r (same for every column)
  f32x4 bias[4];
#pragma unroll
  for (int mt = 0; mt < 4; ++mt)
#pragma unroll
    for (int r = 0; r < 4; ++r) {
      const int r0 = 64 * w + 16 * mt + 4 * q + r;
      bias[mt][r] = bih[r0] + bhh[r0];
    }
  // column-split ownership: column lane n owns (m-tile n>>2, reg n&3)
  const int mt_sel  = n >> 2;
  const int reg_sel = n & 3;
  const int row_own = 64 * w + 16 * mt_sel + 4 * q + reg_sel;

  // ---- h0 = 0; stage x block 0 (256 thr x 8 floats = 32 steps x 64 floats)
  hbuf[0][tid] = (_Float16)0.f;
  {
    float4 v0 = *(const float4*)(xb + tid * 8);
    float4 v1 = *(const float4*)(xb + tid * 8 + 4);
    f16x8 d = { (_Float16)v0.x, (_Float16)v0.y, (_Float16)v0.z, (_Float16)v0.w,
                (_Float16)v1.x, (_Float16)v1.y, (_Float16)v1.z, (_Float16)v1.w };
    *(f16x8*)(xbuf[0] + tid * 8) = d;
  }
  __syncthreads();

  // ---- main recurrence: one __syncthreads per step (h double-buffered)
  int t = 0;
  for (int blk = 0; t < len; ++blk) {
    float4 pre0, pre1;
    const bool havepre = ((blk + 1) * XBLK < len);
    if (havepre) {
      const float* ps = xb + (size_t)(blk + 1) * XBLK * nI + tid * 8;
      pre0 = *(const float4*)ps;
      pre1 = *(const float4*)(ps + 4);
    }

    const int nsteps = min(XBLK, len - blk * XBLK);
    const _Float16* xB = xbuf[blk & 1];

    for (int s = 0; s < nsteps; ++s, ++t) {
      const _Float16* hsrc = hbuf[t & 1];
      const _Float16* xsrc = xB + s * nI;

      f32x4 acc0 = bias[0], acc1 = bias[1], acc2 = bias[2], acc3 = bias[3];
      // W_hh . h : 8 K-tiles; B-frag broadcast across columns, shared by 4 mt
#pragma unroll
      for (int kt = 0; kt < 8; ++kt) {
        f16x8 Bh = *(const f16x8*)(hsrc + 32 * kt + 8 * q);
        acc0 = __builtin_amdgcn_mfma_f32_16x16x32_f16(Ah[0][kt], Bh, acc0, 0, 0, 0);
        acc1 = __builtin_amdgcn_mfma_f32_16x16x32_f16(Ah[1][kt], Bh, acc1, 0, 0, 0);
        acc2 = __builtin_amdgcn_mfma_f32_16x16x32_f16(Ah[2][kt], Bh, acc2, 0, 0, 0);
        acc3 = __builtin_amdgcn_mfma_f32_16x16x32_f16(Ah[3][kt], Bh, acc3, 0, 0, 0);
      }
      // W_ih . x_t : 2 K-tiles (fused input projection)
#pragma unroll
      for (int kt = 0; kt < 2; ++kt) {
        f16x8 Bx = *(const f16x8*)(xsrc + 32 * kt + 8 * q);
        acc0 = __builtin_amdgcn_mfma_f32_16x16x32_f16(Ax[0][kt], Bx, acc0, 0, 0, 0);
        acc1 = __builtin_amdgcn_mfma_f32_16x16x32_f16(Ax[1][kt], Bx, acc1, 0, 0, 0);
        acc2 = __builtin_amdgcn_mfma_f32_16x16x32_f16(Ax[2][kt], Bx, acc2, 0, 0, 0);
        acc3 = __builtin_amdgcn_mfma_f32_16x16x32_f16(Ax[3][kt], Bx, acc3, 0, 0, 0);
      }

      // explicit selects (no dynamically-indexed array -> no scratch)
      f32x4 ax = (n & 4) ? acc1 : acc0;
      f32x4 ay = (n & 4) ? acc3 : acc2;
      f32x4 a  = (n & 8) ? ay : ax;
      float lo = (reg_sel & 1) ? a[1] : a[0];
      float hi = (reg_sel & 1) ? a[3] : a[2];
      float v  = (reg_sel & 2) ? hi : lo;
      float hn = fast_tanh(v);

      // fold next-x staging write in before this block's final step barrier
      if (s == nsteps - 1 && havepre) {
        f16x8 d = { (_Float16)pre0.x, (_Float16)pre0.y, (_Float16)pre0.z, (_Float16)pre0.w,
                    (_Float16)pre1.x, (_Float16)pre1.y, (_Float16)pre1.z, (_Float16)pre1.w };
        *(f16x8*)(xbuf[(blk + 1) & 1] + tid * 8) = d;
      }
      hbuf[(t + 1) & 1][row_own] = (_Float16)hn;   // every lane writes exactly one
      __syncthreads();
    }
  }

  // ---- epilogue: out[b] = h_final . W_fc + b_fc
  float v = (float)hbuf[len & 1][tid] * Wfc[tid];
#pragma unroll
  for (int off = 32; off; off >>= 1) v += __shfl_down(v, off);
  if (l == 0) red[w] = v;
  __syncthreads();
  if (tid == 0) out[b] = ((red[0] + red[1]) + (red[2] + red[3])) + bfc[0];
}

extern "C" void kernel_launch(void* const* d_in, const int* in_sizes, int n_in,
                              void* d_out, int out_size, void* d_ws, size_t ws_size,
                              hipStream_t stream) {
  const float* x   = (const float*)d_in[0];
  const int* lens  = (const int*)d_in[1];
  const float* Wih = (const float*)d_in[2];
  const float* Whh = (const float*)d_in[3];
  const float* bih = (const float*)d_in[4];
  const float* bhh = (const float*)d_in[5];
  const float* Wfc = (const float*)d_in[6];
  const float* bfc = (const float*)d_in[7];
  float* out = (float*)d_out;

  rnn_mfma4<<<nB, THREADS, 0, stream>>>(x, lens, Wih, Whh, bih, bhh, Wfc, bfc, out);
}

// Round 4
// 1267.936 us; speedup vs baseline: 1.1460x; 1.1460x over previous
//
#include <hip/hip_runtime.h>

// RNN B=256 T=2048 I=64 H=256 — one WG/sample, 256 CUs, MFMA matvec.
// Round 4 vs round 2 (best, 1218us):
//  (a) input projection xp = x W_ih^T + b removed from the per-step MFMA
//      chain: produced in-kernel per 16-step block (4 MFMA/wave per block,
//      amortized 0.25/step) into LDS f32, consumed as accumulator INIT via
//      one broadcast ds_read_b128 per m-tile. 20 -> 16 MFMA/wave/step.
//  (b) per-step barrier is lgkmcnt-only (raw s_barrier): __syncthreads drains
//      vmcnt(0) which would stall on the global x prefetch every block.
// 8 waves (2/SIMD, round 2 beat round 3 decisively), weights in VGPR A-frags,
// h double-buffered in LDS f16.

static constexpr int nB = 256;
static constexpr int nT = 2048;
static constexpr int nI = 64;
static constexpr int nH = 256;
static constexpr int XPB = 16;        // timesteps per xp block
static constexpr int XPS = nH + 4;    // xp row stride (f32): 16B-aligned rows
static constexpr int THREADS = 512;   // 8 waves; wave w owns rows [32w,32w+32)

typedef _Float16 f16x8 __attribute__((ext_vector_type(8)));
typedef float f32x4 __attribute__((ext_vector_type(4)));

__device__ __forceinline__ void barrier_lgkm() {
  // LDS-visibility barrier that does NOT drain vmcnt: global prefetch loads
  // issued at block top stay in flight across the per-step barriers.
  asm volatile("s_waitcnt lgkmcnt(0)\n\ts_barrier" ::: "memory");
}

__device__ __forceinline__ float fast_tanh(float x) {
  float a = fabsf(x);
  float e = __expf(-2.0f * a);            // in (0,1], never overflows
  float r = (1.0f - e) / (1.0f + e);
  return copysignf(r, x);
}

__global__ __launch_bounds__(THREADS, 2)
void rnn_v4(const float* __restrict__ x, const int* __restrict__ lengths,
            const float* __restrict__ Wih, const float* __restrict__ Whh,
            const float* __restrict__ bih, const float* __restrict__ bhh,
            const float* __restrict__ Wfc, const float* __restrict__ bfc,
            float* __restrict__ out)
{
  __shared__ __align__(16) _Float16 hbuf[2][nH];        // 1 KB
  __shared__ __align__(16) float xpb[2][XPB * XPS];     // 32.5 KB
  __shared__ float red[8];

  const int b   = blockIdx.x;
  const int tid = threadIdx.x;
  const int w   = tid >> 6;       // wave 0..7
  const int l   = tid & 63;
  const int q   = l >> 4;         // quad 0..3
  const int n   = l & 15;         // MFMA row/col lane
  const int len = lengths[b];     // in [1, nT]
  const float* xb = x + (size_t)b * nT * nI;

  // ---- W_hh A-fragments (resident): wave w rows [32w,32w+32) = 2 m-tiles.
  // A layout (16x16x32): lane holds A[m=lane&15][k=8*(lane>>4)+j], j=0..7.
  f16x8 Ah[2][8];
#pragma unroll
  for (int mt = 0; mt < 2; ++mt) {
    const int row = 32 * w + 16 * mt + n;
#pragma unroll
    for (int kt = 0; kt < 8; ++kt) {
      const float* src = Whh + row * nH + 32 * kt + 8 * q;
      f16x8 a;
#pragma unroll
      for (int j = 0; j < 8; ++j) a[j] = (_Float16)src[j];
      Ah[mt][kt] = a;
    }
  }
  // ---- W_ih^T B-fragments for xp production (resident): wave w produces
  // h-columns [32w,32w+32) = 2 n-tiles. B[k][h] = Wih[h][k].
  f16x8 Bp[2][2];
  float biasp[2];
#pragma unroll
  for (int ntl = 0; ntl < 2; ++ntl) {
    const int hcol = 32 * w + 16 * ntl + n;
#pragma unroll
    for (int kt = 0; kt < 2; ++kt) {
      const float* src = Wih + hcol * nI + 32 * kt + 8 * q;
      f16x8 a;
#pragma unroll
      for (int j = 0; j < 8; ++j) a[j] = (_Float16)src[j];
      Bp[ntl][kt] = a;
    }
    biasp[ntl] = bih[hcol] + bhh[hcol];   // bias folded into xp at production
  }
  // column-split ownership for h write: lane n<8 owns (m-tile n>>2, reg n&3)
  const int mt_sel  = (n >> 2) & 1;
  const int reg_sel = n & 3;
  const int row_own = 32 * w + 16 * mt_sel + 4 * q + reg_sel;

  // ---- produce xp block 0 (t=0..15) into xpb[0]; h0 = 0
  {
    const float* pr = xb + (size_t)n * nI + 8 * q;  // A row m=n -> x[t=n]
    float4 x0 = *(const float4*)(pr);
    float4 x1 = *(const float4*)(pr + 4);
    float4 x2 = *(const float4*)(pr + 32);
    float4 x3 = *(const float4*)(pr + 36);
    f16x8 A0 = { (_Float16)x0.x,(_Float16)x0.y,(_Float16)x0.z,(_Float16)x0.w,
                 (_Float16)x1.x,(_Float16)x1.y,(_Float16)x1.z,(_Float16)x1.w };
    f16x8 A1 = { (_Float16)x2.x,(_Float16)x2.y,(_Float16)x2.z,(_Float16)x2.w,
                 (_Float16)x3.x,(_Float16)x3.y,(_Float16)x3.z,(_Float16)x3.w };
#pragma unroll
    for (int ntl = 0; ntl < 2; ++ntl) {
      f32x4 c = { biasp[ntl], biasp[ntl], biasp[ntl], biasp[ntl] };
      c = __builtin_amdgcn_mfma_f32_16x16x32_f16(A0, Bp[ntl][0], c, 0, 0, 0);
      c = __builtin_amdgcn_mfma_f32_16x16x32_f16(A1, Bp[ntl][1], c, 0, 0, 0);
      const int hc = 32 * w + 16 * ntl + n;
#pragma unroll
      for (int r = 0; r < 4; ++r) xpb[0][(4 * q + r) * XPS + hc] = c[r];
    }
  }
  if (tid < nH) hbuf[0][tid] = (_Float16)0.f;
  __syncthreads();

  // ---- main recurrence
  int t = 0;
  for (int blk = 0; t < len; ++blk) {
    const int t0n = (blk + 1) * XPB;
    const bool havenext = t0n < len;
    // prefetch x for the NEXT block's production (global, stays in flight
    // across the lgkm-only per-step barriers; consumed at block end)
    float4 x0, x1, x2, x3;
    if (havenext) {
      const float* pr = xb + (size_t)(t0n + n) * nI + 8 * q;
      x0 = *(const float4*)(pr);
      x1 = *(const float4*)(pr + 4);
      x2 = *(const float4*)(pr + 32);
      x3 = *(const float4*)(pr + 36);
    }

    const int nsteps = min(XPB, len - blk * XPB);
    const float* xpsrc = xpb[blk & 1];

    for (int s = 0; s < nsteps; ++s, ++t) {
      const _Float16* hsrc = hbuf[t & 1];

      // accumulator init = precomputed xp (+bias): broadcast b128 per m-tile
      f32x4 acc0 = *(const f32x4*)(xpsrc + s * XPS + 32 * w + 4 * q);
      f32x4 acc1 = *(const f32x4*)(xpsrc + s * XPS + 32 * w + 16 + 4 * q);

      // W_hh . h : 8 K-tiles (the only per-step MFMA work)
#pragma unroll
      for (int kt = 0; kt < 8; ++kt) {
        f16x8 Bh = *(const f16x8*)(hsrc + 32 * kt + 8 * q);
        acc0 = __builtin_amdgcn_mfma_f32_16x16x32_f16(Ah[0][kt], Bh, acc0, 0, 0, 0);
        acc1 = __builtin_amdgcn_mfma_f32_16x16x32_f16(Ah[1][kt], Bh, acc1, 0, 0, 0);
      }

      // every column holds a valid copy; lane n<8 finishes one output row
      f32x4 a = mt_sel ? acc1 : acc0;
      float lo = (reg_sel & 1) ? a[1] : a[0];
      float hi = (reg_sel & 1) ? a[3] : a[2];
      float v  = (reg_sel & 2) ? hi : lo;
      float hn = fast_tanh(v);

      // produce next xp block during the last step of this block
      if (s == nsteps - 1 && havenext) {
        f16x8 A0 = { (_Float16)x0.x,(_Float16)x0.y,(_Float16)x0.z,(_Float16)x0.w,
                     (_Float16)x1.x,(_Float16)x1.y,(_Float16)x1.z,(_Float16)x1.w };
        f16x8 A1 = { (_Float16)x2.x,(_Float16)x2.y,(_Float16)x2.z,(_Float16)x2.w,
                     (_Float16)x3.x,(_Float16)x3.y,(_Float16)x3.z,(_Float16)x3.w };
        float* dst = xpb[(blk + 1) & 1];
#pragma unroll
        for (int ntl = 0; ntl < 2; ++ntl) {
          f32x4 c = { biasp[ntl], biasp[ntl], biasp[ntl], biasp[ntl] };
          c = __builtin_amdgcn_mfma_f32_16x16x32_f16(A0, Bp[ntl][0], c, 0, 0, 0);
          c = __builtin_amdgcn_mfma_f32_16x16x32_f16(A1, Bp[ntl][1], c, 0, 0, 0);
          const int hc = 32 * w + 16 * ntl + n;
#pragma unroll
          for (int r = 0; r < 4; ++r) dst[(4 * q + r) * XPS + hc] = c[r];
        }
      }

      if (n < 8) hbuf[(t + 1) & 1][row_own] = (_Float16)hn;
      barrier_lgkm();
    }
  }

  // ---- epilogue: out[b] = h_final . W_fc + b_fc
  float v = 0.f;
  if (tid < nH) v = (float)hbuf[len & 1][tid] * Wfc[tid];
#pragma unroll
  for (int off = 32; off; off >>= 1) v += __shfl_down(v, off);
  if (l == 0) red[w] = v;
  __syncthreads();
  if (tid == 0) {
    float acc = bfc[0];
#pragma unroll
    for (int i = 0; i < 8; ++i) acc += red[i];
    out[b] = acc;
  }
}

extern "C" void kernel_launch(void* const* d_in, const int* in_sizes, int n_in,
                              void* d_out, int out_size, void* d_ws, size_t ws_size,
                              hipStream_t stream) {
  const float* x   = (const float*)d_in[0];
  const int* lens  = (const int*)d_in[1];
  const float* Wih = (const float*)d_in[2];
  const float* Whh = (const float*)d_in[3];
  const float* bih = (const float*)d_in[4];
  const float* bhh = (const float*)d_in[5];
  const float* Wfc = (const float*)d_in[6];
  const float* bfc = (const float*)d_in[7];
  float* out = (float*)d_out;

  rnn_v4<<<nB, THREADS, 0, stream>>>(x, lens, Wih, Whh, bih, bhh, Wfc, bfc, out);
}